// Round 1
// baseline (6147.577 us; speedup 1.0000x reference)
//
#include <hip/hip_runtime.h>
#include <hip/hip_bf16.h>
#include <math.h>

#define T_SEQ 2048

__device__ __forceinline__ float bflo(unsigned u){ return __uint_as_float(u << 16); }
__device__ __forceinline__ float bfhi(unsigned u){ return __uint_as_float(u & 0xffff0000u); }

// C[M,N] = A[M,K] @ B[N,K]^T   (fp32, K % 16 == 0, M % 128 == 0, N % 8 == 0)
__global__ __launch_bounds__(256) void gemm_bt(const float* __restrict__ A,
                                               const float* __restrict__ B,
                                               float* __restrict__ C,
                                               int M, int N, int K)
{
    __shared__ __align__(16) float As[16][132];   // [k][m], +4 pad
    __shared__ __align__(16) float Bs[16][132];   // [k][n]
    const int tid = threadIdx.x;
    const int tx = tid & 15, ty = tid >> 4;
    const int m0 = blockIdx.y * 128, n0 = blockIdx.x * 128;
    float acc[8][8] = {};
    for (int k0 = 0; k0 < K; k0 += 16) {
        #pragma unroll
        for (int pass = 0; pass < 2; pass++) {
            int idx = tid + 256 * pass;           // 0..511
            int r = idx >> 2;                     // 0..127
            int c4 = (idx & 3) << 2;              // 0,4,8,12
            float4 av = *reinterpret_cast<const float4*>(&A[(size_t)(m0 + r) * K + k0 + c4]);
            As[c4 + 0][r] = av.x; As[c4 + 1][r] = av.y;
            As[c4 + 2][r] = av.z; As[c4 + 3][r] = av.w;
            float4 bv;
            if (n0 + r < N) bv = *reinterpret_cast<const float4*>(&B[(size_t)(n0 + r) * K + k0 + c4]);
            else { bv.x = bv.y = bv.z = bv.w = 0.f; }
            Bs[c4 + 0][r] = bv.x; Bs[c4 + 1][r] = bv.y;
            Bs[c4 + 2][r] = bv.z; Bs[c4 + 3][r] = bv.w;
        }
        __syncthreads();
        #pragma unroll
        for (int kk = 0; kk < 16; kk++) {
            float4 a0 = *reinterpret_cast<const float4*>(&As[kk][ty * 8]);
            float4 a1 = *reinterpret_cast<const float4*>(&As[kk][ty * 8 + 4]);
            float4 b0 = *reinterpret_cast<const float4*>(&Bs[kk][tx * 8]);
            float4 b1 = *reinterpret_cast<const float4*>(&Bs[kk][tx * 8 + 4]);
            float a[8] = {a0.x, a0.y, a0.z, a0.w, a1.x, a1.y, a1.z, a1.w};
            float b[8] = {b0.x, b0.y, b0.z, b0.w, b1.x, b1.y, b1.z, b1.w};
            #pragma unroll
            for (int i = 0; i < 8; i++)
                #pragma unroll
                for (int j = 0; j < 8; j++)
                    acc[i][j] = fmaf(a[i], b[j], acc[i][j]);
        }
        __syncthreads();
    }
    #pragma unroll
    for (int i = 0; i < 8; i++) {
        size_t row = m0 + ty * 8 + i;
        int col = n0 + tx * 8;
        if (col < N) {
            float4 c0, c1;
            c0.x = acc[i][0]; c0.y = acc[i][1]; c0.z = acc[i][2]; c0.w = acc[i][3];
            c1.x = acc[i][4]; c1.y = acc[i][5]; c1.z = acc[i][6]; c1.w = acc[i][7];
            *reinterpret_cast<float4*>(&C[row * (size_t)N + col]) = c0;
            *reinterpret_cast<float4*>(&C[row * (size_t)N + col + 4]) = c1;
        }
    }
}

// Fused causal flash attention with RoPE applied at tile-load time.
// qbuf: (4096,2048) q per head h at cols h*128..; qrot: (4096,1024) h*64..;
// krot: (4096,64); ukv: (4096,4096) head h: k at h*256.., v at h*256+128..
// obuf: (4096,2048) output, head-major cols.
__global__ __launch_bounds__(256) void flash_attn(
    const float* __restrict__ qbuf, const float* __restrict__ qrot,
    const float* __restrict__ krot, const float* __restrict__ ukv,
    float* __restrict__ obuf)
{
    __shared__ __align__(16) __hip_bfloat16 Qst[192][64];  // [d][row], transposed
    __shared__ __align__(16) __hip_bfloat16 Kst[192][64];
    __shared__ __align__(16) __hip_bfloat16 Vs[64][128];   // exactly 64 KiB total

    const int tid = threadIdx.x;
    const int tx = tid & 15, ty = tid >> 4;
    const int qt = blockIdx.x, bh = blockIdx.y;
    const int b = bh >> 4, h = bh & 15;
    const int q0 = qt * 64;
    const float SCALE = 0.07216878364870323f;    // 1/sqrt(192)
    const float L2B = 0.4152410118609203f;       // log2(10000)/32

    // ---- stage Q (RoPE on last 64 dims, pre-scaled) ----
    for (int e = tid; e < 64 * 192; e += 256) {
        int c = e >> 6, r = e & 63;              // c wave-uniform, r = lane
        int t = q0 + r;
        size_t g = (size_t)b * T_SEQ + t;
        float val;
        if (c < 128) {
            val = qbuf[g * 2048 + h * 128 + c];
        } else {
            int j = c - 128;
            int fi = j & 31;
            float freq = exp2f(-L2B * (float)fi);
            float ang = (float)t * freq;
            float sn, cs;
            sincosf(ang, &sn, &cs);
            const float* qr = qrot + g * 1024 + h * 64;
            float xv = qr[j];
            float rot = (j < 32) ? -qr[j + 32] : qr[j - 32];
            val = xv * cs + rot * sn;
        }
        Qst[c][r] = __float2bfloat16(val * SCALE);
    }

    float O[4][8] = {};                          // rows ty+16i, dims tx*8+dd
    float m_i[4] = {-INFINITY, -INFINITY, -INFINITY, -INFINITY};
    float l_i[4] = {};

    const int nkt = qt + 1;
    for (int kt = 0; kt < nkt; kt++) {
        const int k0 = kt * 64;
        __syncthreads();                         // prior reads done before restage
        // ---- stage K (RoPE on last 64) ----
        for (int e = tid; e < 64 * 192; e += 256) {
            int c = e >> 6, r = e & 63;
            int t = k0 + r;
            size_t g = (size_t)b * T_SEQ + t;
            float val;
            if (c < 128) {
                val = ukv[g * 4096 + h * 256 + c];
            } else {
                int j = c - 128;
                int fi = j & 31;
                float freq = exp2f(-L2B * (float)fi);
                float ang = (float)t * freq;
                float sn, cs;
                sincosf(ang, &sn, &cs);
                const float* kr = krot + g * 64;
                float xv = kr[j];
                float rot = (j < 32) ? -kr[j + 32] : kr[j - 32];
                val = xv * cs + rot * sn;
            }
            Kst[c][r] = __float2bfloat16(val);
        }
        // ---- stage V ----
        for (int e = tid; e < 64 * 128; e += 256) {
            int r = e >> 7, c = e & 127;
            size_t g = (size_t)b * T_SEQ + k0 + r;
            Vs[r][c] = __float2bfloat16(ukv[g * 4096 + h * 256 + 128 + c]);
        }
        __syncthreads();

        // ---- S = Q K^T  (4q x 4k per thread) ----
        float s[4][4] = {};
        #pragma unroll 8
        for (int d = 0; d < 192; d++) {
            float a[4], kb[4];
            #pragma unroll
            for (int i = 0; i < 4; i++) a[i] = __bfloat162float(Qst[d][ty + 16 * i]);
            #pragma unroll
            for (int j = 0; j < 4; j++) kb[j] = __bfloat162float(Kst[d][tx + 16 * j]);
            #pragma unroll
            for (int i = 0; i < 4; i++)
                #pragma unroll
                for (int j = 0; j < 4; j++)
                    s[i][j] = fmaf(a[i], kb[j], s[i][j]);
        }

        // ---- causal mask + online softmax (row groups of 16 lanes) ----
        float p[4][4], alpha[4];
        #pragma unroll
        for (int i = 0; i < 4; i++) {
            const int qpos = q0 + ty + 16 * i;
            #pragma unroll
            for (int j = 0; j < 4; j++) {
                const int kpos = k0 + tx + 16 * j;
                if (kpos > qpos) s[i][j] = -INFINITY;
            }
            float rmax = fmaxf(fmaxf(s[i][0], s[i][1]), fmaxf(s[i][2], s[i][3]));
            rmax = fmaxf(rmax, __shfl_xor(rmax, 1, 64));
            rmax = fmaxf(rmax, __shfl_xor(rmax, 2, 64));
            rmax = fmaxf(rmax, __shfl_xor(rmax, 4, 64));
            rmax = fmaxf(rmax, __shfl_xor(rmax, 8, 64));
            float mnew = fmaxf(m_i[i], rmax);    // finite after first tile
            alpha[i] = __expf(m_i[i] - mnew);    // exp(-inf)=0 on first tile
            m_i[i] = mnew;
            float sum = 0.f;
            #pragma unroll
            for (int j = 0; j < 4; j++) { p[i][j] = __expf(s[i][j] - mnew); sum += p[i][j]; }
            sum += __shfl_xor(sum, 1, 64);
            sum += __shfl_xor(sum, 2, 64);
            sum += __shfl_xor(sum, 4, 64);
            sum += __shfl_xor(sum, 8, 64);
            l_i[i] = l_i[i] * alpha[i] + sum;
            #pragma unroll
            for (int dd = 0; dd < 8; dd++) O[i][dd] *= alpha[i];
        }

        // ---- O += P V  (P broadcast via shfl within 16-lane row group) ----
        const int srcbase = (tid & 48);
        #pragma unroll
        for (int j = 0; j < 4; j++) {
            #pragma unroll
            for (int kk = 0; kk < 16; kk++) {
                const int k = 16 * j + kk;
                uint4 u = *reinterpret_cast<const uint4*>(&Vs[k][tx * 8]);
                float vv[8] = {bflo(u.x), bfhi(u.x), bflo(u.y), bfhi(u.y),
                               bflo(u.z), bfhi(u.z), bflo(u.w), bfhi(u.w)};
                #pragma unroll
                for (int i = 0; i < 4; i++) {
                    float pvi = __shfl(p[i][j], srcbase | kk, 64);
                    #pragma unroll
                    for (int dd = 0; dd < 8; dd++)
                        O[i][dd] = fmaf(pvi, vv[dd], O[i][dd]);
                }
            }
        }
    }

    // ---- epilogue ----
    #pragma unroll
    for (int i = 0; i < 4; i++) {
        int t = q0 + ty + 16 * i;
        size_t base = ((size_t)(b * T_SEQ + t)) * 2048 + h * 128 + tx * 8;
        float inv = 1.0f / l_i[i];
        float4 o0, o1;
        o0.x = O[i][0] * inv; o0.y = O[i][1] * inv; o0.z = O[i][2] * inv; o0.w = O[i][3] * inv;
        o1.x = O[i][4] * inv; o1.y = O[i][5] * inv; o1.z = O[i][6] * inv; o1.w = O[i][7] * inv;
        *reinterpret_cast<float4*>(&obuf[base]) = o0;
        *reinterpret_cast<float4*>(&obuf[base + 4]) = o1;
    }
}

extern "C" void kernel_launch(void* const* d_in, const int* in_sizes, int n_in,
                              void* d_out, int out_size, void* d_ws, size_t ws_size,
                              hipStream_t stream)
{
    const float* x      = (const float*)d_in[0];
    const float* w_q    = (const float*)d_in[1];
    const float* w_dkv  = (const float*)d_in[2];
    const float* w_ukv  = (const float*)d_in[3];
    const float* w_o    = (const float*)d_in[4];
    const float* w_qrot = (const float*)d_in[5];
    const float* w_krot = (const float*)d_in[6];
    // d_in[7] = mask: deterministic causal triu, applied analytically in-kernel
    float* out = (float*)d_out;

    const size_t M = 4096;                 // B*T
    float* ws  = (float*)d_ws;
    float* qb  = ws;                       // 4096x2048
    float* qr  = qb + M * 2048;            // 4096x1024
    float* kr  = qr + M * 1024;            // 4096x64
    float* dkv = kr + M * 64;              // 4096x512
    float* ukv = dkv + M * 512;            // 4096x4096
    float* ao  = ukv + M * 4096;           // 4096x2048  (~153 MB total)

    dim3 blk(256);
    gemm_bt<<<dim3(16, 32), blk, 0, stream>>>(x,   w_q,    qb,  4096, 2048, 2048);
    gemm_bt<<<dim3(8,  32), blk, 0, stream>>>(x,   w_qrot, qr,  4096, 1024, 2048);
    gemm_bt<<<dim3(1,  32), blk, 0, stream>>>(x,   w_krot, kr,  4096, 64,   2048);
    gemm_bt<<<dim3(4,  32), blk, 0, stream>>>(x,   w_dkv,  dkv, 4096, 512,  2048);
    gemm_bt<<<dim3(32, 32), blk, 0, stream>>>(dkv, w_ukv,  ukv, 4096, 4096, 512);
    flash_attn<<<dim3(32, 32), blk, 0, stream>>>(qb, qr, kr, ukv, ao);
    gemm_bt<<<dim3(16, 32), blk, 0, stream>>>(ao,  w_o,    out, 4096, 2048, 2048);
}

// Round 2
// 2441.758 us; speedup vs baseline: 2.5177x; 2.5177x over previous
//
#include <hip/hip_runtime.h>
#include <hip/hip_bf16.h>
#include <math.h>

#define T_SEQ 2048

typedef __bf16 bf16x8 __attribute__((ext_vector_type(8)));
typedef float  f32x4  __attribute__((ext_vector_type(4)));

// C[M,N] = A[M,K] @ B[N,K]^T   (fp32, K % 16 == 0, M % 128 == 0, N % 8 == 0)
__global__ __launch_bounds__(256) void gemm_bt(const float* __restrict__ A,
                                               const float* __restrict__ B,
                                               float* __restrict__ C,
                                               int M, int N, int K)
{
    __shared__ __align__(16) float As[16][132];
    __shared__ __align__(16) float Bs[16][132];
    const int tid = threadIdx.x;
    const int tx = tid & 15, ty = tid >> 4;
    const int m0 = blockIdx.y * 128, n0 = blockIdx.x * 128;
    float acc[8][8] = {};
    for (int k0 = 0; k0 < K; k0 += 16) {
        #pragma unroll
        for (int pass = 0; pass < 2; pass++) {
            int idx = tid + 256 * pass;
            int r = idx >> 2;
            int c4 = (idx & 3) << 2;
            float4 av = *reinterpret_cast<const float4*>(&A[(size_t)(m0 + r) * K + k0 + c4]);
            As[c4 + 0][r] = av.x; As[c4 + 1][r] = av.y;
            As[c4 + 2][r] = av.z; As[c4 + 3][r] = av.w;
            float4 bv;
            if (n0 + r < N) bv = *reinterpret_cast<const float4*>(&B[(size_t)(n0 + r) * K + k0 + c4]);
            else { bv.x = bv.y = bv.z = bv.w = 0.f; }
            Bs[c4 + 0][r] = bv.x; Bs[c4 + 1][r] = bv.y;
            Bs[c4 + 2][r] = bv.z; Bs[c4 + 3][r] = bv.w;
        }
        __syncthreads();
        #pragma unroll
        for (int kk = 0; kk < 16; kk++) {
            float4 a0 = *reinterpret_cast<const float4*>(&As[kk][ty * 8]);
            float4 a1 = *reinterpret_cast<const float4*>(&As[kk][ty * 8 + 4]);
            float4 b0 = *reinterpret_cast<const float4*>(&Bs[kk][tx * 8]);
            float4 b1 = *reinterpret_cast<const float4*>(&Bs[kk][tx * 8 + 4]);
            float a[8] = {a0.x, a0.y, a0.z, a0.w, a1.x, a1.y, a1.z, a1.w};
            float b[8] = {b0.x, b0.y, b0.z, b0.w, b1.x, b1.y, b1.z, b1.w};
            #pragma unroll
            for (int i = 0; i < 8; i++)
                #pragma unroll
                for (int j = 0; j < 8; j++)
                    acc[i][j] = fmaf(a[i], b[j], acc[i][j]);
        }
        __syncthreads();
    }
    #pragma unroll
    for (int i = 0; i < 8; i++) {
        size_t row = m0 + ty * 8 + i;
        int col = n0 + tx * 8;
        if (col < N) {
            float4 c0, c1;
            c0.x = acc[i][0]; c0.y = acc[i][1]; c0.z = acc[i][2]; c0.w = acc[i][3];
            c1.x = acc[i][4]; c1.y = acc[i][5]; c1.z = acc[i][6]; c1.w = acc[i][7];
            *reinterpret_cast<float4*>(&C[row * (size_t)N + col]) = c0;
            *reinterpret_cast<float4*>(&C[row * (size_t)N + col + 4]) = c1;
        }
    }
}

// MFMA flash attention. Per block: one (b,h), two Q-tiles of 128 (paired p and
// 15-p for uniform load). K-tiles of 64 staged in LDS (bf16, RoPE fused), Q in
// register A-frags, P via LDS round-trip (m120 pattern).
// qbuf (4096,2048) head h at cols h*128; qrot (4096,1024) h*64;
// krot (4096,64); ukv (4096,4096) head h: K at h*256, V at h*256+128;
// obuf (4096,2048).
__global__ __launch_bounds__(256, 1) void flash_mfma(
    const float* __restrict__ qbuf, const float* __restrict__ qrot,
    const float* __restrict__ krot, const float* __restrict__ ukv,
    float* __restrict__ obuf)
{
    constexpr int KS = 200;   // K LDS stride: 192 + 8 pad (bf16 el) -> 400B
    constexpr int VS = 72;    // Vt stride: 64 + 8 -> 144B
    constexpr int PS = 72;    // Ps stride
    __shared__ __align__(16) __bf16 Ks[64 * KS];    // [k][d]  25600 B
    __shared__ __align__(16) __bf16 Vt[128 * VS];   // [dv][k] 18432 B
    __shared__ __align__(16) __bf16 Psh[128 * PS];  // [q][k]  18432 B

    const int tid  = threadIdx.x;
    const int w    = tid >> 6;        // wave 0..3: q rows 32w..32w+31
    const int lane = tid & 63;
    const int l15  = lane & 15;
    const int quad = lane >> 4;
    const int p  = blockIdx.x;        // q-tile pair 0..7
    const int bh = blockIdx.y;
    const int b  = bh >> 4, h = bh & 15;
    const float SCALE = 0.07216878364870323f;   // 1/sqrt(192)
    const float L2B   = 0.4152410118609203f;    // log2(10000)/32

    for (int half = 0; half < 2; half++) {
        const int qi = half ? (15 - p) : p;
        const int q0 = qi * 128;

        // ---- Q fragments (A-layout), RoPE fused, pre-scaled ----
        bf16x8 qf[2][6];
        #pragma unroll
        for (int rt = 0; rt < 2; rt++) {
            const int q = q0 + 32 * w + 16 * rt + l15;
            const size_t g = (size_t)b * T_SEQ + q;
            const float* qrow = qbuf + g * 2048 + h * 128;
            #pragma unroll
            for (int dt = 0; dt < 4; dt++) {
                const float* src = qrow + 32 * dt + 8 * quad;
                float4 a = *reinterpret_cast<const float4*>(src);
                float4 c = *reinterpret_cast<const float4*>(src + 4);
                bf16x8 f;
                f[0]=(__bf16)(a.x*SCALE); f[1]=(__bf16)(a.y*SCALE);
                f[2]=(__bf16)(a.z*SCALE); f[3]=(__bf16)(a.w*SCALE);
                f[4]=(__bf16)(c.x*SCALE); f[5]=(__bf16)(c.y*SCALE);
                f[6]=(__bf16)(c.z*SCALE); f[7]=(__bf16)(c.w*SCALE);
                qf[rt][dt] = f;
            }
            const float* qrr = qrot + g * 1024 + h * 64;
            #pragma unroll
            for (int dt = 4; dt < 6; dt++) {
                const int j0 = 32 * (dt - 4) + 8 * quad;
                bf16x8 f;
                #pragma unroll
                for (int jj = 0; jj < 8; jj++) {
                    int j = j0 + jj, fi = j & 31;
                    float freq = exp2f(-L2B * (float)fi);
                    float sn, cs;
                    __sincosf((float)q * freq, &sn, &cs);
                    float xv  = qrr[j];
                    float rot = (j < 32) ? -qrr[j + 32] : qrr[j - 32];
                    f[jj] = (__bf16)((xv * cs + rot * sn) * SCALE);
                }
                qf[rt][dt] = f;
            }
        }

        f32x4 o[2][8];
        float m_i[2][4], l_i[2][4];
        #pragma unroll
        for (int rt = 0; rt < 2; rt++) {
            #pragma unroll
            for (int dt = 0; dt < 8; dt++) { o[rt][dt][0]=0.f; o[rt][dt][1]=0.f; o[rt][dt][2]=0.f; o[rt][dt][3]=0.f; }
            #pragma unroll
            for (int r = 0; r < 4; r++) { m_i[rt][r] = -INFINITY; l_i[rt][r] = 0.f; }
        }

        const int nunits = 2 * qi + 2;
        for (int u = 0; u < nunits; u++) {
            const int k0 = 64 * u;
            __syncthreads();                     // prior PV reads done

            // ---- stage K nope dims [k][0..127] via b128 rows ----
            #pragma unroll
            for (int i = 0; i < 4; i++) {
                int krow = (tid >> 4) + 16 * i;
                int d8   = (tid & 15) * 8;
                size_t g = (size_t)b * T_SEQ + k0 + krow;
                const float* src = ukv + g * 4096 + h * 256 + d8;
                float4 a = *reinterpret_cast<const float4*>(src);
                float4 c = *reinterpret_cast<const float4*>(src + 4);
                bf16x8 f;
                f[0]=(__bf16)a.x; f[1]=(__bf16)a.y; f[2]=(__bf16)a.z; f[3]=(__bf16)a.w;
                f[4]=(__bf16)c.x; f[5]=(__bf16)c.y; f[6]=(__bf16)c.z; f[7]=(__bf16)c.w;
                *reinterpret_cast<bf16x8*>(Ks + krow * KS + d8) = f;
            }
            // ---- stage K rope dims [k][128..191] ----
            #pragma unroll
            for (int i = 0; i < 16; i++) {
                int e = tid + 256 * i;
                int krow = e >> 6, j = e & 63, fi = j & 31;
                int t = k0 + krow;
                size_t g = (size_t)b * T_SEQ + t;
                const float* kr = krot + g * 64;
                float freq = exp2f(-L2B * (float)fi);
                float sn, cs;
                __sincosf((float)t * freq, &sn, &cs);
                float xv  = kr[j];
                float rot = (j < 32) ? -kr[j + 32] : kr[j - 32];
                Ks[krow * KS + 128 + j] = (__bf16)(xv * cs + rot * sn);
            }
            // ---- stage V transposed: Vt[dv][k] via register transpose ----
            #pragma unroll
            for (int i = 0; i < 4; i++) {
                int uid = tid + 256 * i;
                int dv = uid & 127, k8 = (uid >> 7) * 8;
                bf16x8 f;
                #pragma unroll
                for (int jj = 0; jj < 8; jj++) {
                    size_t g = (size_t)b * T_SEQ + k0 + k8 + jj;
                    f[jj] = (__bf16)ukv[g * 4096 + h * 256 + 128 + dv];
                }
                *reinterpret_cast<bf16x8*>(Vt + dv * VS + k8) = f;
            }
            __syncthreads();

            // ---- S = Q K^T : 2 row-tiles x 4 k-subtiles, d = 6 x 32 ----
            f32x4 s[2][4];
            #pragma unroll
            for (int rt = 0; rt < 2; rt++)
                #pragma unroll
                for (int kt = 0; kt < 4; kt++) { s[rt][kt][0]=0.f; s[rt][kt][1]=0.f; s[rt][kt][2]=0.f; s[rt][kt][3]=0.f; }
            #pragma unroll
            for (int kt = 0; kt < 4; kt++) {
                #pragma unroll
                for (int dt = 0; dt < 6; dt++) {
                    bf16x8 kf = *reinterpret_cast<const bf16x8*>(Ks + (16 * kt + l15) * KS + 32 * dt + 8 * quad);
                    s[0][kt] = __builtin_amdgcn_mfma_f32_16x16x32_bf16(qf[0][dt], kf, s[0][kt], 0, 0, 0);
                    s[1][kt] = __builtin_amdgcn_mfma_f32_16x16x32_bf16(qf[1][dt], kf, s[1][kt], 0, 0, 0);
                }
            }

            // ---- causal mask + online softmax (C layout: col=l15, row=4*quad+reg) ----
            #pragma unroll
            for (int rt = 0; rt < 2; rt++) {
                #pragma unroll
                for (int r = 0; r < 4; r++) {
                    const int q = q0 + 32 * w + 16 * rt + 4 * quad + r;
                    float sv[4];
                    #pragma unroll
                    for (int kt = 0; kt < 4; kt++) {
                        int kpos = k0 + 16 * kt + l15;
                        sv[kt] = (kpos > q) ? -INFINITY : s[rt][kt][r];
                    }
                    float rmax = fmaxf(fmaxf(sv[0], sv[1]), fmaxf(sv[2], sv[3]));
                    rmax = fmaxf(rmax, __shfl_xor(rmax, 1, 64));
                    rmax = fmaxf(rmax, __shfl_xor(rmax, 2, 64));
                    rmax = fmaxf(rmax, __shfl_xor(rmax, 4, 64));
                    rmax = fmaxf(rmax, __shfl_xor(rmax, 8, 64));
                    float mnew  = fmaxf(m_i[rt][r], rmax);
                    float alpha = __expf(m_i[rt][r] - mnew);
                    m_i[rt][r] = mnew;
                    float sum = 0.f;
                    #pragma unroll
                    for (int kt = 0; kt < 4; kt++) {
                        float pv = __expf(sv[kt] - mnew);
                        sum += pv;
                        Psh[(32 * w + 16 * rt + 4 * quad + r) * PS + 16 * kt + l15] = (__bf16)pv;
                    }
                    sum += __shfl_xor(sum, 1, 64);
                    sum += __shfl_xor(sum, 2, 64);
                    sum += __shfl_xor(sum, 4, 64);
                    sum += __shfl_xor(sum, 8, 64);
                    l_i[rt][r] = l_i[rt][r] * alpha + sum;
                    #pragma unroll
                    for (int dt = 0; dt < 8; dt++) o[rt][dt][r] *= alpha;
                }
            }
            __syncthreads();                     // Psh visible

            // ---- O += P V : P as A-frag from LDS, V as B-frag from Vt ----
            #pragma unroll
            for (int kh = 0; kh < 2; kh++) {
                bf16x8 pf0 = *reinterpret_cast<const bf16x8*>(Psh + (32 * w + l15) * PS + 32 * kh + 8 * quad);
                bf16x8 pf1 = *reinterpret_cast<const bf16x8*>(Psh + (32 * w + 16 + l15) * PS + 32 * kh + 8 * quad);
                #pragma unroll
                for (int dt = 0; dt < 8; dt++) {
                    bf16x8 vf = *reinterpret_cast<const bf16x8*>(Vt + (16 * dt + l15) * VS + 32 * kh + 8 * quad);
                    o[0][dt] = __builtin_amdgcn_mfma_f32_16x16x32_bf16(pf0, vf, o[0][dt], 0, 0, 0);
                    o[1][dt] = __builtin_amdgcn_mfma_f32_16x16x32_bf16(pf1, vf, o[1][dt], 0, 0, 0);
                }
            }
        }

        // ---- epilogue ----
        #pragma unroll
        for (int rt = 0; rt < 2; rt++) {
            #pragma unroll
            for (int r = 0; r < 4; r++) {
                const int q = q0 + 32 * w + 16 * rt + 4 * quad + r;
                const float inv = 1.0f / l_i[rt][r];
                size_t base = ((size_t)b * T_SEQ + q) * 2048 + h * 128;
                #pragma unroll
                for (int dt = 0; dt < 8; dt++)
                    obuf[base + 16 * dt + l15] = o[rt][dt][r] * inv;
            }
        }
    }
}

extern "C" void kernel_launch(void* const* d_in, const int* in_sizes, int n_in,
                              void* d_out, int out_size, void* d_ws, size_t ws_size,
                              hipStream_t stream)
{
    const float* x      = (const float*)d_in[0];
    const float* w_q    = (const float*)d_in[1];
    const float* w_dkv  = (const float*)d_in[2];
    const float* w_ukv  = (const float*)d_in[3];
    const float* w_o    = (const float*)d_in[4];
    const float* w_qrot = (const float*)d_in[5];
    const float* w_krot = (const float*)d_in[6];
    float* out = (float*)d_out;

    const size_t M = 4096;
    float* ws  = (float*)d_ws;
    float* qb  = ws;                       // 4096x2048
    float* qr  = qb + M * 2048;            // 4096x1024
    float* kr  = qr + M * 1024;            // 4096x64
    float* dkv = kr + M * 64;              // 4096x512
    float* ukv = dkv + M * 512;            // 4096x4096
    float* ao  = ukv + M * 4096;           // 4096x2048

    dim3 blk(256);
    gemm_bt<<<dim3(16, 32), blk, 0, stream>>>(x,   w_q,    qb,  4096, 2048, 2048);
    gemm_bt<<<dim3(8,  32), blk, 0, stream>>>(x,   w_qrot, qr,  4096, 1024, 2048);
    gemm_bt<<<dim3(1,  32), blk, 0, stream>>>(x,   w_krot, kr,  4096, 64,   2048);
    gemm_bt<<<dim3(4,  32), blk, 0, stream>>>(x,   w_dkv,  dkv, 4096, 512,  2048);
    gemm_bt<<<dim3(32, 32), blk, 0, stream>>>(dkv, w_ukv,  ukv, 4096, 4096, 512);
    flash_mfma<<<dim3(8, 32), blk, 0, stream>>>(qb, qr, kr, ukv, ao);
    gemm_bt<<<dim3(16, 32), blk, 0, stream>>>(ao,  w_o,    out, 4096, 2048, 2048);
}

// Round 3
// 792.716 us; speedup vs baseline: 7.7551x; 3.0802x over previous
//
#include <hip/hip_runtime.h>
#include <hip/hip_bf16.h>
#include <math.h>

#define T_SEQ 2048

typedef __bf16 bf16x8 __attribute__((ext_vector_type(8)));
typedef float  f32x4  __attribute__((ext_vector_type(4)));

#define GLOAD_LDS16(g, l) __builtin_amdgcn_global_load_lds( \
    (const __attribute__((address_space(1))) void*)(g),      \
    (__attribute__((address_space(3))) void*)(l), 16, 0, 0)

// ---------------- fp32 -> bf16 cast (8 el/thread) ----------------
__global__ __launch_bounds__(256) void cast_bf16(const float* __restrict__ src,
                                                 __bf16* __restrict__ dst, int n)
{
    int i = (blockIdx.x * 256 + threadIdx.x) * 8;
    if (i < n) {
        float4 a = *reinterpret_cast<const float4*>(src + i);
        float4 b = *reinterpret_cast<const float4*>(src + i + 4);
        bf16x8 f;
        f[0] = (__bf16)a.x; f[1] = (__bf16)a.y; f[2] = (__bf16)a.z; f[3] = (__bf16)a.w;
        f[4] = (__bf16)b.x; f[5] = (__bf16)b.y; f[6] = (__bf16)b.z; f[7] = (__bf16)b.w;
        *reinterpret_cast<bf16x8*>(dst + i) = f;
    }
}

// ---------------- bf16 MFMA GEMM: C[M,N] = A[M,K] @ B[N,K]^T ----------------
// m97 structure: 128x128 tile, BK=32, 4 waves x 4x4 frags of 16x16x32,
// global_load_lds width 16. M%128==0, K%32==0; N clamped (store-guarded).
template <typename OutT>
__global__ __launch_bounds__(256) void gemm_bt_mfma(const __bf16* __restrict__ A,
                                                    const __bf16* __restrict__ B,
                                                    OutT* __restrict__ C,
                                                    int M, int N, int K)
{
    __shared__ __align__(16) __bf16 As[128 * 32];   // [row][k] 64B/row
    __shared__ __align__(16) __bf16 Bs[128 * 32];
    const int tid  = threadIdx.x;
    const int lane = tid & 63, w = tid >> 6;
    const int l15  = lane & 15, quad = lane >> 4;
    const int wm = w >> 1, wn = w & 1;
    const int m0 = blockIdx.y * 128, n0 = blockIdx.x * 128;

    // staging: wave w covers rows 32w..32w+31 (two issues of 16 rows)
    const int srow = lane >> 2;          // 0..15
    const int scol = (lane & 3) * 8;     // 0,8,16,24
    const __bf16* Ap0 = A + (size_t)(m0 + 32 * w + srow) * K + scol;
    const __bf16* Ap1 = Ap0 + (size_t)16 * K;
    int bn = n0 + 32 * w + srow;
    const __bf16* Bp0 = B + (size_t)(bn      < N ? bn      : N - 1) * K + scol;
    const __bf16* Bp1 = B + (size_t)(bn + 16 < N ? bn + 16 : N - 1) * K + scol;
    __bf16* AsW = As + w * 1024 + lane * 8;   // lane*16 bytes
    __bf16* BsW = Bs + w * 1024 + lane * 8;

    f32x4 acc[4][4] = {};

    for (int k0 = 0; k0 < K; k0 += 32) {
        GLOAD_LDS16(Ap0 + k0, AsW);
        GLOAD_LDS16(Ap1 + k0, AsW + 512);
        GLOAD_LDS16(Bp0 + k0, BsW);
        GLOAD_LDS16(Bp1 + k0, BsW + 512);
        __syncthreads();

        bf16x8 af[4], bfr[4];
        #pragma unroll
        for (int mi = 0; mi < 4; mi++)
            af[mi] = *reinterpret_cast<const bf16x8*>(As + (wm * 64 + mi * 16 + l15) * 32 + quad * 8);
        #pragma unroll
        for (int ni = 0; ni < 4; ni++)
            bfr[ni] = *reinterpret_cast<const bf16x8*>(Bs + (wn * 64 + ni * 16 + l15) * 32 + quad * 8);
        #pragma unroll
        for (int mi = 0; mi < 4; mi++)
            #pragma unroll
            for (int ni = 0; ni < 4; ni++)
                acc[mi][ni] = __builtin_amdgcn_mfma_f32_16x16x32_bf16(af[mi], bfr[ni], acc[mi][ni], 0, 0, 0);
        __syncthreads();
    }

    #pragma unroll
    for (int mi = 0; mi < 4; mi++) {
        #pragma unroll
        for (int ni = 0; ni < 4; ni++) {
            int col = n0 + wn * 64 + ni * 16 + l15;
            if (col < N) {
                #pragma unroll
                for (int r = 0; r < 4; r++) {
                    size_t row = m0 + wm * 64 + mi * 16 + quad * 4 + r;
                    C[row * (size_t)N + col] = (OutT)acc[mi][ni][r];
                }
            }
        }
    }
}

// ---------------- MFMA flash attention (bf16 in/out) ----------------
// qbuf (4096,2048) head h cols h*128; qrot (4096,1024) h*64; krot (4096,64);
// ukv (4096,4096) head h: K at h*256, V at h*256+128; obuf (4096,2048) bf16.
__global__ __launch_bounds__(256, 1) void flash_mfma(
    const __bf16* __restrict__ qbuf, const __bf16* __restrict__ qrot,
    const __bf16* __restrict__ krot, const __bf16* __restrict__ ukv,
    __bf16* __restrict__ obuf)
{
    constexpr int KS = 200;
    constexpr int VS = 72;
    constexpr int PS = 72;
    __shared__ __align__(16) __bf16 Ks[64 * KS];
    __shared__ __align__(16) __bf16 Vt[128 * VS];
    __shared__ __align__(16) __bf16 Psh[128 * PS];

    const int tid  = threadIdx.x;
    const int w    = tid >> 6;
    const int lane = tid & 63;
    const int l15  = lane & 15;
    const int quad = lane >> 4;
    const int p  = blockIdx.x;
    const int bh = blockIdx.y;
    const int b  = bh >> 4, h = bh & 15;
    const float SCALE = 0.07216878364870323f;   // 1/sqrt(192), folded into softmax
    const float L2B   = 0.4152410118609203f;    // log2(10000)/32

    for (int half = 0; half < 2; half++) {
        const int qi = half ? (15 - p) : p;
        const int q0 = qi * 128;

        // ---- Q fragments (A-layout), RoPE fused on dims 128..191 ----
        bf16x8 qf[2][6];
        #pragma unroll
        for (int rt = 0; rt < 2; rt++) {
            const int q = q0 + 32 * w + 16 * rt + l15;
            const size_t g = (size_t)b * T_SEQ + q;
            const __bf16* qrow = qbuf + g * 2048 + h * 128;
            #pragma unroll
            for (int dt = 0; dt < 4; dt++)
                qf[rt][dt] = *reinterpret_cast<const bf16x8*>(qrow + 32 * dt + 8 * quad);
            const __bf16* qrr = qrot + g * 1024 + h * 64;
            #pragma unroll
            for (int dt = 4; dt < 6; dt++) {
                const int j0 = 32 * (dt - 4) + 8 * quad;
                bf16x8 f;
                #pragma unroll
                for (int jj = 0; jj < 8; jj++) {
                    int j = j0 + jj, fi = j & 31;
                    float freq = exp2f(-L2B * (float)fi);
                    float sn, cs;
                    __sincosf((float)q * freq, &sn, &cs);
                    float xv  = (float)qrr[j];
                    float rot = (j < 32) ? -(float)qrr[j + 32] : (float)qrr[j - 32];
                    f[jj] = (__bf16)(xv * cs + rot * sn);
                }
                qf[rt][dt] = f;
            }
        }

        f32x4 o[2][8];
        float m_i[2][4], l_i[2][4];
        #pragma unroll
        for (int rt = 0; rt < 2; rt++) {
            #pragma unroll
            for (int dt = 0; dt < 8; dt++) { o[rt][dt][0]=0.f; o[rt][dt][1]=0.f; o[rt][dt][2]=0.f; o[rt][dt][3]=0.f; }
            #pragma unroll
            for (int r = 0; r < 4; r++) { m_i[rt][r] = -INFINITY; l_i[rt][r] = 0.f; }
        }

        const int nunits = 2 * qi + 2;
        for (int u = 0; u < nunits; u++) {
            const int k0 = 64 * u;
            __syncthreads();

            // ---- stage K nope dims [k][0..127] ----
            #pragma unroll
            for (int i = 0; i < 4; i++) {
                int krow = (tid >> 4) + 16 * i;
                int d8   = (tid & 15) * 8;
                size_t g = (size_t)b * T_SEQ + k0 + krow;
                *reinterpret_cast<bf16x8*>(Ks + krow * KS + d8) =
                    *reinterpret_cast<const bf16x8*>(ukv + g * 4096 + h * 256 + d8);
            }
            // ---- stage K rope dims [k][128..191] ----
            #pragma unroll
            for (int i = 0; i < 16; i++) {
                int e = tid + 256 * i;
                int krow = e >> 6, j = e & 63, fi = j & 31;
                int t = k0 + krow;
                size_t g = (size_t)b * T_SEQ + t;
                const __bf16* kr = krot + g * 64;
                float freq = exp2f(-L2B * (float)fi);
                float sn, cs;
                __sincosf((float)t * freq, &sn, &cs);
                float xv  = (float)kr[j];
                float rot = (j < 32) ? -(float)kr[j + 32] : (float)kr[j - 32];
                Ks[krow * KS + 128 + j] = (__bf16)(xv * cs + rot * sn);
            }
            // ---- stage V transposed: Vt[dv][k] ----
            #pragma unroll
            for (int i = 0; i < 4; i++) {
                int uid = tid + 256 * i;
                int dv = uid & 127, k8 = (uid >> 7) * 8;
                bf16x8 f;
                #pragma unroll
                for (int jj = 0; jj < 8; jj++) {
                    size_t g = (size_t)b * T_SEQ + k0 + k8 + jj;
                    f[jj] = ukv[g * 4096 + h * 256 + 128 + dv];
                }
                *reinterpret_cast<bf16x8*>(Vt + dv * VS + k8) = f;
            }
            __syncthreads();

            // ---- S = Q K^T ----
            f32x4 s[2][4] = {};
            #pragma unroll
            for (int kt = 0; kt < 4; kt++) {
                #pragma unroll
                for (int dt = 0; dt < 6; dt++) {
                    bf16x8 kf = *reinterpret_cast<const bf16x8*>(Ks + (16 * kt + l15) * KS + 32 * dt + 8 * quad);
                    s[0][kt] = __builtin_amdgcn_mfma_f32_16x16x32_bf16(qf[0][dt], kf, s[0][kt], 0, 0, 0);
                    s[1][kt] = __builtin_amdgcn_mfma_f32_16x16x32_bf16(qf[1][dt], kf, s[1][kt], 0, 0, 0);
                }
            }

            // ---- causal mask + online softmax (C layout: col=l15, row=4*quad+r) ----
            #pragma unroll
            for (int rt = 0; rt < 2; rt++) {
                #pragma unroll
                for (int r = 0; r < 4; r++) {
                    const int q = q0 + 32 * w + 16 * rt + 4 * quad + r;
                    float sv[4];
                    #pragma unroll
                    for (int kt = 0; kt < 4; kt++) {
                        int kpos = k0 + 16 * kt + l15;
                        sv[kt] = (kpos > q) ? -INFINITY : s[rt][kt][r] * SCALE;
                    }
                    float rmax = fmaxf(fmaxf(sv[0], sv[1]), fmaxf(sv[2], sv[3]));
                    rmax = fmaxf(rmax, __shfl_xor(rmax, 1, 64));
                    rmax = fmaxf(rmax, __shfl_xor(rmax, 2, 64));
                    rmax = fmaxf(rmax, __shfl_xor(rmax, 4, 64));
                    rmax = fmaxf(rmax, __shfl_xor(rmax, 8, 64));
                    float mnew  = fmaxf(m_i[rt][r], rmax);
                    float alpha = __expf(m_i[rt][r] - mnew);
                    m_i[rt][r] = mnew;
                    float sum = 0.f;
                    #pragma unroll
                    for (int kt = 0; kt < 4; kt++) {
                        float pv = __expf(sv[kt] - mnew);
                        sum += pv;
                        Psh[(32 * w + 16 * rt + 4 * quad + r) * PS + 16 * kt + l15] = (__bf16)pv;
                    }
                    sum += __shfl_xor(sum, 1, 64);
                    sum += __shfl_xor(sum, 2, 64);
                    sum += __shfl_xor(sum, 4, 64);
                    sum += __shfl_xor(sum, 8, 64);
                    l_i[rt][r] = l_i[rt][r] * alpha + sum;
                    #pragma unroll
                    for (int dt = 0; dt < 8; dt++) o[rt][dt][r] *= alpha;
                }
            }
            __syncthreads();

            // ---- O += P V ----
            #pragma unroll
            for (int kh = 0; kh < 2; kh++) {
                bf16x8 pf0 = *reinterpret_cast<const bf16x8*>(Psh + (32 * w + l15) * PS + 32 * kh + 8 * quad);
                bf16x8 pf1 = *reinterpret_cast<const bf16x8*>(Psh + (32 * w + 16 + l15) * PS + 32 * kh + 8 * quad);
                #pragma unroll
                for (int dt = 0; dt < 8; dt++) {
                    bf16x8 vf = *reinterpret_cast<const bf16x8*>(Vt + (16 * dt + l15) * VS + 32 * kh + 8 * quad);
                    o[0][dt] = __builtin_amdgcn_mfma_f32_16x16x32_bf16(pf0, vf, o[0][dt], 0, 0, 0);
                    o[1][dt] = __builtin_amdgcn_mfma_f32_16x16x32_bf16(pf1, vf, o[1][dt], 0, 0, 0);
                }
            }
        }

        // ---- epilogue (bf16 out) ----
        #pragma unroll
        for (int rt = 0; rt < 2; rt++) {
            #pragma unroll
            for (int r = 0; r < 4; r++) {
                const int q = q0 + 32 * w + 16 * rt + 4 * quad + r;
                const float inv = 1.0f / l_i[rt][r];
                size_t base = ((size_t)b * T_SEQ + q) * 2048 + h * 128;
                #pragma unroll
                for (int dt = 0; dt < 8; dt++)
                    obuf[base + 16 * dt + l15] = (__bf16)(o[rt][dt][r] * inv);
            }
        }
    }
}

extern "C" void kernel_launch(void* const* d_in, const int* in_sizes, int n_in,
                              void* d_out, int out_size, void* d_ws, size_t ws_size,
                              hipStream_t stream)
{
    const float* x      = (const float*)d_in[0];
    const float* w_q    = (const float*)d_in[1];
    const float* w_dkv  = (const float*)d_in[2];
    const float* w_ukv  = (const float*)d_in[3];
    const float* w_o    = (const float*)d_in[4];
    const float* w_qrot = (const float*)d_in[5];
    const float* w_krot = (const float*)d_in[6];
    float* out = (float*)d_out;

    const size_t M = 4096;
    __bf16* ws   = (__bf16*)d_ws;
    __bf16* xb   = ws;                    // 4096x2048
    __bf16* wqb  = xb   + M * 2048;       // 2048x2048
    __bf16* wdkb = wqb  + 2048 * 2048;    // 512x2048
    __bf16* wukb = wdkb + 512 * 2048;     // 4096x512
    __bf16* wob  = wukb + 4096 * 512;     // 2048x2048
    __bf16* wqrb = wob  + 2048 * 2048;    // 1024x2048
    __bf16* wkrb = wqrb + 1024 * 2048;    // 64x2048
    __bf16* qb   = wkrb + 64 * 2048;      // 4096x2048
    __bf16* qr   = qb   + M * 2048;       // 4096x1024
    __bf16* kr   = qr   + M * 1024;       // 4096x64
    __bf16* dkv  = kr   + M * 64;         // 4096x512
    __bf16* ukv  = dkv  + M * 512;        // 4096x4096
    __bf16* ao   = ukv  + M * 4096;       // 4096x2048   (~124 MB total)

    dim3 blk(256);
    cast_bf16<<<4096, blk, 0, stream>>>(x,      xb,   4096 * 2048);
    cast_bf16<<<2048, blk, 0, stream>>>(w_q,    wqb,  2048 * 2048);
    cast_bf16<<<512,  blk, 0, stream>>>(w_dkv,  wdkb, 512 * 2048);
    cast_bf16<<<1024, blk, 0, stream>>>(w_ukv,  wukb, 4096 * 512);
    cast_bf16<<<2048, blk, 0, stream>>>(w_o,    wob,  2048 * 2048);
    cast_bf16<<<1024, blk, 0, stream>>>(w_qrot, wqrb, 1024 * 2048);
    cast_bf16<<<64,   blk, 0, stream>>>(w_krot, wkrb, 64 * 2048);

    gemm_bt_mfma<__bf16><<<dim3(16, 32), blk, 0, stream>>>(xb,  wqb,  qb,  4096, 2048, 2048);
    gemm_bt_mfma<__bf16><<<dim3(8,  32), blk, 0, stream>>>(xb,  wqrb, qr,  4096, 1024, 2048);
    gemm_bt_mfma<__bf16><<<dim3(1,  32), blk, 0, stream>>>(xb,  wkrb, kr,  4096, 64,   2048);
    gemm_bt_mfma<__bf16><<<dim3(4,  32), blk, 0, stream>>>(xb,  wdkb, dkv, 4096, 512,  2048);
    gemm_bt_mfma<__bf16><<<dim3(32, 32), blk, 0, stream>>>(dkv, wukb, ukv, 4096, 4096, 512);
    flash_mfma<<<dim3(8, 32), blk, 0, stream>>>(qb, qr, kr, ukv, ao);
    gemm_bt_mfma<float><<<dim3(16, 32), blk, 0, stream>>>(ao, wob, out, 4096, 2048, 2048);
}

// Round 4
// 640.144 us; speedup vs baseline: 9.6034x; 1.2383x over previous
//
#include <hip/hip_runtime.h>
#include <hip/hip_bf16.h>
#include <math.h>

#define T_SEQ 2048

typedef __bf16 bf16x8 __attribute__((ext_vector_type(8)));
typedef float  f32x4  __attribute__((ext_vector_type(4)));

#define GLOAD_LDS16(g, l) __builtin_amdgcn_global_load_lds( \
    (const __attribute__((address_space(1))) void*)(g),      \
    (__attribute__((address_space(3))) void*)(l), 16, 0, 0)

// ---------------- fp32 -> bf16 cast (8 el/thread) ----------------
__global__ __launch_bounds__(256) void cast_bf16(const float* __restrict__ src,
                                                 __bf16* __restrict__ dst, int n)
{
    int i = (blockIdx.x * 256 + threadIdx.x) * 8;
    if (i < n) {
        float4 a = *reinterpret_cast<const float4*>(src + i);
        float4 b = *reinterpret_cast<const float4*>(src + i + 4);
        bf16x8 f;
        f[0] = (__bf16)a.x; f[1] = (__bf16)a.y; f[2] = (__bf16)a.z; f[3] = (__bf16)a.w;
        f[4] = (__bf16)b.x; f[5] = (__bf16)b.y; f[6] = (__bf16)b.z; f[7] = (__bf16)b.w;
        *reinterpret_cast<bf16x8*>(dst + i) = f;
    }
}

// ---------------- in-place RoPE over 64-el head blocks ----------------
// buf rows of 2^(shift+1) elements; 2^shift work units/row (nheadblk*32).
// unit = (hb, j<32): rotates pair (j, j+32) with angle t * base^(-j/32).
__global__ __launch_bounds__(256) void rope_ip(__bf16* buf, int shift, int total)
{
    int gid = blockIdx.x * 256 + threadIdx.x;
    if (gid >= total) return;
    int row = gid >> shift;
    int rem = gid & ((1 << shift) - 1);
    int hb = rem >> 5, j = rem & 31;
    int t = row & (T_SEQ - 1);
    const float L2B = 0.4152410118609203f;      // log2(10000)/32
    float freq = exp2f(-L2B * (float)j);
    float sn, cs;
    __sincosf((float)t * freq, &sn, &cs);
    size_t base = ((size_t)row << (shift + 1)) + hb * 64 + j;
    float v1 = (float)buf[base], v2 = (float)buf[base + 32];
    buf[base]      = (__bf16)(v1 * cs - v2 * sn);
    buf[base + 32] = (__bf16)(v2 * cs + v1 * sn);
}

// ---------------- V pre-transpose: vtt[bh][u][dv(128)][k(64), stride 72] ----
__global__ __launch_bounds__(256) void prep_v(const __bf16* __restrict__ ukv,
                                              __bf16* __restrict__ vtt)
{
    __shared__ __align__(16) __bf16 Ls[64 * 136];
    const int tid = threadIdx.x;
    const int u = blockIdx.x, bh = blockIdx.y;
    const int b = bh >> 4, h = bh & 15;
    const size_t base = (size_t)b * T_SEQ + u * 64;
    #pragma unroll
    for (int p = 0; p < 4; p++) {
        int c = tid + 256 * p;
        int k = c >> 4, dv8 = (c & 15) * 8;
        *reinterpret_cast<bf16x8*>(Ls + k * 136 + dv8) =
            *reinterpret_cast<const bf16x8*>(ukv + (base + k) * 4096 + h * 256 + 128 + dv8);
    }
    __syncthreads();
    #pragma unroll
    for (int p = 0; p < 4; p++) {
        int c = tid + 256 * p;
        int dv = c >> 3, k8 = (c & 7) * 8;
        bf16x8 f;
        #pragma unroll
        for (int i = 0; i < 8; i++) f[i] = Ls[(k8 + i) * 136 + dv];
        *reinterpret_cast<bf16x8*>(vtt + (((size_t)bh * 32 + u) * 128 + dv) * 72 + k8) = f;
    }
}

// ---------------- bf16 MFMA GEMM: C[M,N] = A[M,K] @ B[N,K]^T ----------------
template <typename OutT>
__global__ __launch_bounds__(256) void gemm_bt_mfma(const __bf16* __restrict__ A,
                                                    const __bf16* __restrict__ B,
                                                    OutT* __restrict__ C,
                                                    int M, int N, int K)
{
    __shared__ __align__(16) __bf16 As[128 * 32];
    __shared__ __align__(16) __bf16 Bs[128 * 32];
    const int tid  = threadIdx.x;
    const int lane = tid & 63, w = tid >> 6;
    const int l15  = lane & 15, quad = lane >> 4;
    const int wm = w >> 1, wn = w & 1;
    const int m0 = blockIdx.y * 128, n0 = blockIdx.x * 128;

    const int srow = lane >> 2;
    const int scol = (lane & 3) * 8;
    const __bf16* Ap0 = A + (size_t)(m0 + 32 * w + srow) * K + scol;
    const __bf16* Ap1 = Ap0 + (size_t)16 * K;
    int bn = n0 + 32 * w + srow;
    const __bf16* Bp0 = B + (size_t)(bn      < N ? bn      : N - 1) * K + scol;
    const __bf16* Bp1 = B + (size_t)(bn + 16 < N ? bn + 16 : N - 1) * K + scol;
    __bf16* AsW = As + w * 1024 + lane * 8;
    __bf16* BsW = Bs + w * 1024 + lane * 8;

    f32x4 acc[4][4] = {};

    for (int k0 = 0; k0 < K; k0 += 32) {
        GLOAD_LDS16(Ap0 + k0, AsW);
        GLOAD_LDS16(Ap1 + k0, AsW + 512);
        GLOAD_LDS16(Bp0 + k0, BsW);
        GLOAD_LDS16(Bp1 + k0, BsW + 512);
        __syncthreads();

        bf16x8 af[4], bfr[4];
        #pragma unroll
        for (int mi = 0; mi < 4; mi++)
            af[mi] = *reinterpret_cast<const bf16x8*>(As + (wm * 64 + mi * 16 + l15) * 32 + quad * 8);
        #pragma unroll
        for (int ni = 0; ni < 4; ni++)
            bfr[ni] = *reinterpret_cast<const bf16x8*>(Bs + (wn * 64 + ni * 16 + l15) * 32 + quad * 8);
        #pragma unroll
        for (int mi = 0; mi < 4; mi++)
            #pragma unroll
            for (int ni = 0; ni < 4; ni++)
                acc[mi][ni] = __builtin_amdgcn_mfma_f32_16x16x32_bf16(af[mi], bfr[ni], acc[mi][ni], 0, 0, 0);
        __syncthreads();
    }

    #pragma unroll
    for (int mi = 0; mi < 4; mi++) {
        #pragma unroll
        for (int ni = 0; ni < 4; ni++) {
            int col = n0 + wn * 64 + ni * 16 + l15;
            if (col < N) {
                #pragma unroll
                for (int r = 0; r < 4; r++) {
                    size_t row = m0 + wm * 64 + mi * 16 + quad * 4 + r;
                    C[row * (size_t)N + col] = (OutT)acc[mi][ni][r];
                }
            }
        }
    }
}

// ---------------- MFMA flash attention (pre-roped inputs) ----------------
// qbuf (4096,2048) head h cols h*128; qrot ROPED (4096,1024) h*64;
// krot ROPED (4096,64); ukv (4096,4096) K at h*256; vtt tiled transposed V.
// Grid (16,32): 512 blocks, one 128-row q-tile each; anti-correlated qi
// mapping so co-resident blocks sum to ~constant work; 2 blocks/CU (62.5KB LDS).
__global__ __launch_bounds__(256, 2) void flash_mfma(
    const __bf16* __restrict__ qbuf, const __bf16* __restrict__ qrot,
    const __bf16* __restrict__ krot, const __bf16* __restrict__ ukv,
    const __bf16* __restrict__ vtt, __bf16* __restrict__ obuf)
{
    constexpr int KS = 200;
    constexpr int VS = 72;
    constexpr int PS = 72;
    __shared__ __align__(16) __bf16 Ks[64 * KS];
    __shared__ __align__(16) __bf16 Vt[128 * VS];
    __shared__ __align__(16) __bf16 Psh[128 * PS];

    const int tid  = threadIdx.x;
    const int w    = tid >> 6;
    const int lane = tid & 63;
    const int l15  = lane & 15;
    const int quad = lane >> 4;
    const int gx = blockIdx.x, gy = blockIdx.y;
    int bh, qi;
    if (gy < 16) { bh = gy * 2;        qi = gx; }
    else         { bh = (gy - 16) * 2 + 1; qi = 15 - gx; }
    const int b = bh >> 4, h = bh & 15;
    const int q0 = qi * 128;
    const float SCALE = 0.07216878364870323f;   // 1/sqrt(192)

    // ---- Q fragments (A-layout), all pre-roped: pure vector loads ----
    bf16x8 qf[2][6];
    #pragma unroll
    for (int rt = 0; rt < 2; rt++) {
        const int q = q0 + 32 * w + 16 * rt + l15;
        const size_t g = (size_t)b * T_SEQ + q;
        const __bf16* qrow = qbuf + g * 2048 + h * 128;
        #pragma unroll
        for (int dt = 0; dt < 4; dt++)
            qf[rt][dt] = *reinterpret_cast<const bf16x8*>(qrow + 32 * dt + 8 * quad);
        const __bf16* qrr = qrot + g * 1024 + h * 64;
        qf[rt][4] = *reinterpret_cast<const bf16x8*>(qrr + 8 * quad);
        qf[rt][5] = *reinterpret_cast<const bf16x8*>(qrr + 32 + 8 * quad);
    }

    f32x4 o[2][8];
    float m_i[2][4], l_i[2][4];
    #pragma unroll
    for (int rt = 0; rt < 2; rt++) {
        #pragma unroll
        for (int dt = 0; dt < 8; dt++) { o[rt][dt][0]=0.f; o[rt][dt][1]=0.f; o[rt][dt][2]=0.f; o[rt][dt][3]=0.f; }
        #pragma unroll
        for (int r = 0; r < 4; r++) { m_i[rt][r] = -INFINITY; l_i[rt][r] = 0.f; }
    }

    const int nunits = 2 * qi + 2;
    const size_t urow = (size_t)b * T_SEQ;
    for (int u = 0; u < nunits; u++) {
        const int k0 = 64 * u;

        // ---- stage K nope [k][0..127]: coalesced vector copies ----
        #pragma unroll
        for (int p = 0; p < 4; p++) {
            int c = tid + 256 * p;
            int row = c >> 4, seg = (c & 15) * 8;
            *reinterpret_cast<bf16x8*>(Ks + row * KS + seg) =
                *reinterpret_cast<const bf16x8*>(ukv + (urow + k0 + row) * 4096 + h * 256 + seg);
        }
        // ---- stage K rope [k][128..191]: pre-roped, contiguous copy ----
        #pragma unroll
        for (int p = 0; p < 2; p++) {
            int c = tid + 256 * p;
            int row = c >> 3, seg = (c & 7) * 8;
            *reinterpret_cast<bf16x8*>(Ks + row * KS + 128 + seg) =
                *reinterpret_cast<const bf16x8*>(krot + (urow + k0 + row) * 64 + seg);
        }
        // ---- stage Vt: flat 18KB copy from pre-transposed tile ----
        {
            const uint4* vsrc = reinterpret_cast<const uint4*>(vtt + ((size_t)bh * 32 + u) * (128 * VS));
            uint4* vdst = reinterpret_cast<uint4*>(Vt);
            for (int c = tid; c < 1152; c += 256) vdst[c] = vsrc[c];
        }
        __syncthreads();

        // ---- S = Q K^T ----
        f32x4 s[2][4] = {};
        #pragma unroll
        for (int kt = 0; kt < 4; kt++) {
            #pragma unroll
            for (int dt = 0; dt < 6; dt++) {
                bf16x8 kf = *reinterpret_cast<const bf16x8*>(Ks + (16 * kt + l15) * KS + 32 * dt + 8 * quad);
                s[0][kt] = __builtin_amdgcn_mfma_f32_16x16x32_bf16(qf[0][dt], kf, s[0][kt], 0, 0, 0);
                s[1][kt] = __builtin_amdgcn_mfma_f32_16x16x32_bf16(qf[1][dt], kf, s[1][kt], 0, 0, 0);
            }
        }

        // ---- causal mask (only near-diagonal units) + online softmax ----
        const bool domask = (u + 2 >= nunits);
        #pragma unroll
        for (int rt = 0; rt < 2; rt++) {
            #pragma unroll
            for (int r = 0; r < 4; r++) {
                const int q = q0 + 32 * w + 16 * rt + 4 * quad + r;
                float sv[4];
                #pragma unroll
                for (int kt = 0; kt < 4; kt++) {
                    float v = s[rt][kt][r] * SCALE;
                    if (domask && (k0 + 16 * kt + l15 > q)) v = -INFINITY;
                    sv[kt] = v;
                }
                float rmax = fmaxf(fmaxf(sv[0], sv[1]), fmaxf(sv[2], sv[3]));
                rmax = fmaxf(rmax, __shfl_xor(rmax, 1, 64));
                rmax = fmaxf(rmax, __shfl_xor(rmax, 2, 64));
                rmax = fmaxf(rmax, __shfl_xor(rmax, 4, 64));
                rmax = fmaxf(rmax, __shfl_xor(rmax, 8, 64));
                float mnew  = fmaxf(m_i[rt][r], rmax);
                float alpha = __expf(m_i[rt][r] - mnew);
                m_i[rt][r] = mnew;
                float sum = 0.f;
                #pragma unroll
                for (int kt = 0; kt < 4; kt++) {
                    float pv = __expf(sv[kt] - mnew);
                    sum += pv;
                    Psh[(32 * w + 16 * rt + 4 * quad + r) * PS + 16 * kt + l15] = (__bf16)pv;
                }
                sum += __shfl_xor(sum, 1, 64);
                sum += __shfl_xor(sum, 2, 64);
                sum += __shfl_xor(sum, 4, 64);
                sum += __shfl_xor(sum, 8, 64);
                l_i[rt][r] = l_i[rt][r] * alpha + sum;
                #pragma unroll
                for (int dt = 0; dt < 8; dt++) o[rt][dt][r] *= alpha;
            }
        }
        // No barrier: Psh rows [32w,32w+32) are written and read by wave w only.

        // ---- O += P V ----
        #pragma unroll
        for (int kh = 0; kh < 2; kh++) {
            bf16x8 pf0 = *reinterpret_cast<const bf16x8*>(Psh + (32 * w + l15) * PS + 32 * kh + 8 * quad);
            bf16x8 pf1 = *reinterpret_cast<const bf16x8*>(Psh + (32 * w + 16 + l15) * PS + 32 * kh + 8 * quad);
            #pragma unroll
            for (int dt = 0; dt < 8; dt++) {
                bf16x8 vf = *reinterpret_cast<const bf16x8*>(Vt + (16 * dt + l15) * VS + 32 * kh + 8 * quad);
                o[0][dt] = __builtin_amdgcn_mfma_f32_16x16x32_bf16(pf0, vf, o[0][dt], 0, 0, 0);
                o[1][dt] = __builtin_amdgcn_mfma_f32_16x16x32_bf16(pf1, vf, o[1][dt], 0, 0, 0);
            }
        }
        __syncthreads();   // all reads of Ks/Vt done before next stage
    }

    // ---- epilogue (bf16 out) ----
    #pragma unroll
    for (int rt = 0; rt < 2; rt++) {
        #pragma unroll
        for (int r = 0; r < 4; r++) {
            const int q = q0 + 32 * w + 16 * rt + 4 * quad + r;
            const float inv = 1.0f / l_i[rt][r];
            size_t base = ((size_t)b * T_SEQ + q) * 2048 + h * 128;
            #pragma unroll
            for (int dt = 0; dt < 8; dt++)
                obuf[base + 16 * dt + l15] = (__bf16)(o[rt][dt][r] * inv);
        }
    }
}

extern "C" void kernel_launch(void* const* d_in, const int* in_sizes, int n_in,
                              void* d_out, int out_size, void* d_ws, size_t ws_size,
                              hipStream_t stream)
{
    const float* x      = (const float*)d_in[0];
    const float* w_q    = (const float*)d_in[1];
    const float* w_dkv  = (const float*)d_in[2];
    const float* w_ukv  = (const float*)d_in[3];
    const float* w_o    = (const float*)d_in[4];
    const float* w_qrot = (const float*)d_in[5];
    const float* w_krot = (const float*)d_in[6];
    float* out = (float*)d_out;

    const size_t M = 4096;
    __bf16* ws   = (__bf16*)d_ws;
    __bf16* xb   = ws;                    // 4096x2048
    __bf16* wqb  = xb   + M * 2048;       // 2048x2048
    __bf16* wdkb = wqb  + 2048 * 2048;    // 512x2048
    __bf16* wukb = wdkb + 512 * 2048;     // 4096x512
    __bf16* wob  = wukb + 4096 * 512;     // 2048x2048
    __bf16* wqrb = wob  + 2048 * 2048;    // 1024x2048
    __bf16* wkrb = wqrb + 1024 * 2048;    // 64x2048
    __bf16* qb   = wkrb + 64 * 2048;      // 4096x2048
    __bf16* qr   = qb   + M * 2048;       // 4096x1024 (roped in place)
    __bf16* kr   = qr   + M * 1024;       // 4096x64   (roped in place)
    __bf16* dkv  = kr   + M * 64;         // 4096x512
    __bf16* ukv  = dkv  + M * 512;        // 4096x4096
    __bf16* ao   = ukv  + M * 4096;       // 4096x2048
    __bf16* vtt  = ao   + M * 2048;       // 32*32*128*72 (~18.9MB)  total ~143MB

    dim3 blk(256);
    cast_bf16<<<4096, blk, 0, stream>>>(x,      xb,   4096 * 2048);
    cast_bf16<<<2048, blk, 0, stream>>>(w_q,    wqb,  2048 * 2048);
    cast_bf16<<<512,  blk, 0, stream>>>(w_dkv,  wdkb, 512 * 2048);
    cast_bf16<<<1024, blk, 0, stream>>>(w_ukv,  wukb, 4096 * 512);
    cast_bf16<<<2048, blk, 0, stream>>>(w_o,    wob,  2048 * 2048);
    cast_bf16<<<1024, blk, 0, stream>>>(w_qrot, wqrb, 1024 * 2048);
    cast_bf16<<<64,   blk, 0, stream>>>(w_krot, wkrb, 64 * 2048);

    gemm_bt_mfma<__bf16><<<dim3(16, 32), blk, 0, stream>>>(xb,  wqb,  qb,  4096, 2048, 2048);
    gemm_bt_mfma<__bf16><<<dim3(8,  32), blk, 0, stream>>>(xb,  wqrb, qr,  4096, 1024, 2048);
    gemm_bt_mfma<__bf16><<<dim3(1,  32), blk, 0, stream>>>(xb,  wkrb, kr,  4096, 64,   2048);
    gemm_bt_mfma<__bf16><<<dim3(4,  32), blk, 0, stream>>>(xb,  wdkb, dkv, 4096, 512,  2048);
    gemm_bt_mfma<__bf16><<<dim3(32, 32), blk, 0, stream>>>(dkv, wukb, ukv, 4096, 4096, 512);

    rope_ip<<<8192, blk, 0, stream>>>(qr, 9, 4096 * 512);   // 16 heads * 32 pairs
    rope_ip<<<512,  blk, 0, stream>>>(kr, 5, 4096 * 32);    // 1 block  * 32 pairs
    prep_v<<<dim3(32, 32), blk, 0, stream>>>(ukv, vtt);

    flash_mfma<<<dim3(16, 32), blk, 0, stream>>>(qb, qr, kr, ukv, vtt, ao);
    gemm_bt_mfma<float><<<dim3(16, 32), blk, 0, stream>>>(ao, wob, out, 4096, 2048, 2048);
}

// Round 8
// 639.780 us; speedup vs baseline: 9.6089x; 1.0006x over previous
//
#include <hip/hip_runtime.h>
#include <hip/hip_bf16.h>
#include <math.h>

#define T_SEQ 2048

typedef __bf16 bf16x8 __attribute__((ext_vector_type(8)));
typedef float  f32x4  __attribute__((ext_vector_type(4)));

#define GLOAD_LDS16(g, l) __builtin_amdgcn_global_load_lds( \
    (const __attribute__((address_space(1))) void*)(g),      \
    (__attribute__((address_space(3))) void*)(l), 16, 0, 0)

// ---------------- fp32 -> bf16 cast (8 el/thread) ----------------
__global__ __launch_bounds__(256) void cast_bf16(const float* __restrict__ src,
                                                 __bf16* __restrict__ dst, int n)
{
    int i = (blockIdx.x * 256 + threadIdx.x) * 8;
    if (i < n) {
        float4 a = *reinterpret_cast<const float4*>(src + i);
        float4 b = *reinterpret_cast<const float4*>(src + i + 4);
        bf16x8 f;
        f[0] = (__bf16)a.x; f[1] = (__bf16)a.y; f[2] = (__bf16)a.z; f[3] = (__bf16)a.w;
        f[4] = (__bf16)b.x; f[5] = (__bf16)b.y; f[6] = (__bf16)b.z; f[7] = (__bf16)b.w;
        *reinterpret_cast<bf16x8*>(dst + i) = f;
    }
}

// ---------------- in-place RoPE over 64-el head blocks ----------------
__global__ __launch_bounds__(256) void rope_ip(__bf16* buf, int shift, int total)
{
    int gid = blockIdx.x * 256 + threadIdx.x;
    if (gid >= total) return;
    int row = gid >> shift;
    int rem = gid & ((1 << shift) - 1);
    int hb = rem >> 5, j = rem & 31;
    int t = row & (T_SEQ - 1);
    const float L2B = 0.4152410118609203f;      // log2(10000)/32
    float freq = exp2f(-L2B * (float)j);
    float sn, cs;
    __sincosf((float)t * freq, &sn, &cs);
    size_t base = ((size_t)row << (shift + 1)) + hb * 64 + j;
    float v1 = (float)buf[base], v2 = (float)buf[base + 32];
    buf[base]      = (__bf16)(v1 * cs - v2 * sn);
    buf[base + 32] = (__bf16)(v2 * cs + v1 * sn);
}

// ---------------- V pre-transpose: vtt[bh][u][dv(128)][k(64), stride 72] ----
__global__ __launch_bounds__(256) void prep_v(const __bf16* __restrict__ ukv,
                                              __bf16* __restrict__ vtt)
{
    __shared__ __align__(16) __bf16 Ls[64 * 136];
    const int tid = threadIdx.x;
    const int u = blockIdx.x, bh = blockIdx.y;
    const int b = bh >> 4, h = bh & 15;
    const size_t base = (size_t)b * T_SEQ + u * 64;
    #pragma unroll
    for (int p = 0; p < 4; p++) {
        int c = tid + 256 * p;
        int k = c >> 4, dv8 = (c & 15) * 8;
        *reinterpret_cast<bf16x8*>(Ls + k * 136 + dv8) =
            *reinterpret_cast<const bf16x8*>(ukv + (base + k) * 4096 + h * 256 + 128 + dv8);
    }
    __syncthreads();
    #pragma unroll
    for (int p = 0; p < 4; p++) {
        int c = tid + 256 * p;
        int dv = c >> 3, k8 = (c & 7) * 8;
        bf16x8 f;
        #pragma unroll
        for (int i = 0; i < 8; i++) f[i] = Ls[(k8 + i) * 136 + dv];
        *reinterpret_cast<bf16x8*>(vtt + (((size_t)bh * 32 + u) * 128 + dv) * 72 + k8) = f;
    }
}

// ---------------- bf16 MFMA GEMM: C[M,N] = A[M,K] @ B[N,K]^T ----------------
template <typename OutT>
__global__ __launch_bounds__(256) void gemm_bt_mfma(const __bf16* __restrict__ A,
                                                    const __bf16* __restrict__ B,
                                                    OutT* __restrict__ C,
                                                    int M, int N, int K)
{
    __shared__ __align__(16) __bf16 As[128 * 32];
    __shared__ __align__(16) __bf16 Bs[128 * 32];
    const int tid  = threadIdx.x;
    const int lane = tid & 63, w = tid >> 6;
    const int l15  = lane & 15, quad = lane >> 4;
    const int wm = w >> 1, wn = w & 1;
    const int m0 = blockIdx.y * 128, n0 = blockIdx.x * 128;

    const int srow = lane >> 2;
    const int scol = (lane & 3) * 8;
    const __bf16* Ap0 = A + (size_t)(m0 + 32 * w + srow) * K + scol;
    const __bf16* Ap1 = Ap0 + (size_t)16 * K;
    int bn = n0 + 32 * w + srow;
    const __bf16* Bp0 = B + (size_t)(bn      < N ? bn      : N - 1) * K + scol;
    const __bf16* Bp1 = B + (size_t)(bn + 16 < N ? bn + 16 : N - 1) * K + scol;
    __bf16* AsW = As + w * 1024 + lane * 8;
    __bf16* BsW = Bs + w * 1024 + lane * 8;

    f32x4 acc[4][4] = {};

    for (int k0 = 0; k0 < K; k0 += 32) {
        GLOAD_LDS16(Ap0 + k0, AsW);
        GLOAD_LDS16(Ap1 + k0, AsW + 512);
        GLOAD_LDS16(Bp0 + k0, BsW);
        GLOAD_LDS16(Bp1 + k0, BsW + 512);
        __syncthreads();

        bf16x8 af[4], bfr[4];
        #pragma unroll
        for (int mi = 0; mi < 4; mi++)
            af[mi] = *reinterpret_cast<const bf16x8*>(As + (wm * 64 + mi * 16 + l15) * 32 + quad * 8);
        #pragma unroll
        for (int ni = 0; ni < 4; ni++)
            bfr[ni] = *reinterpret_cast<const bf16x8*>(Bs + (wn * 64 + ni * 16 + l15) * 32 + quad * 8);
        #pragma unroll
        for (int mi = 0; mi < 4; mi++)
            #pragma unroll
            for (int ni = 0; ni < 4; ni++)
                acc[mi][ni] = __builtin_amdgcn_mfma_f32_16x16x32_bf16(af[mi], bfr[ni], acc[mi][ni], 0, 0, 0);
        __syncthreads();
    }

    #pragma unroll
    for (int mi = 0; mi < 4; mi++) {
        #pragma unroll
        for (int ni = 0; ni < 4; ni++) {
            int col = n0 + wn * 64 + ni * 16 + l15;
            if (col < N) {
                #pragma unroll
                for (int r = 0; r < 4; r++) {
                    size_t row = m0 + wm * 64 + mi * 16 + quad * 4 + r;
                    C[row * (size_t)N + col] = (OutT)acc[mi][ni][r];
                }
            }
        }
    }
}

// ---------------- MFMA flash attention (pre-roped inputs) ----------------
// qbuf (4096,2048) head h cols h*128; qrot ROPED (4096,1024) h*64;
// krot ROPED (4096,64); ukv (4096,4096) K at h*256; vtt tiled transposed V.
// Grid (16,32): 512 blocks, one 128-row q-tile each; anti-correlated qi
// mapping so co-resident blocks sum to ~constant work; 2 blocks/CU (62.5KB LDS).
__global__ __launch_bounds__(256, 2) void flash_mfma(
    const __bf16* __restrict__ qbuf, const __bf16* __restrict__ qrot,
    const __bf16* __restrict__ krot, const __bf16* __restrict__ ukv,
    const __bf16* __restrict__ vtt, __bf16* __restrict__ obuf)
{
    constexpr int KS = 200;
    constexpr int VS = 72;
    constexpr int PS = 72;
    __shared__ __align__(16) __bf16 Ks[64 * KS];
    __shared__ __align__(16) __bf16 Vt[128 * VS];
    __shared__ __align__(16) __bf16 Psh[128 * PS];

    const int tid  = threadIdx.x;
    const int w    = tid >> 6;
    const int lane = tid & 63;
    const int l15  = lane & 15;
    const int quad = lane >> 4;
    const int gx = blockIdx.x, gy = blockIdx.y;
    int bh, qi;
    if (gy < 16) { bh = gy * 2;        qi = gx; }
    else         { bh = (gy - 16) * 2 + 1; qi = 15 - gx; }
    const int b = bh >> 4, h = bh & 15;
    const int q0 = qi * 128;
    const float SCALE = 0.07216878364870323f;   // 1/sqrt(192)

    // ---- Q fragments (A-layout), all pre-roped: pure vector loads ----
    bf16x8 qf[2][6];
    #pragma unroll
    for (int rt = 0; rt < 2; rt++) {
        const int q = q0 + 32 * w + 16 * rt + l15;
        const size_t g = (size_t)b * T_SEQ + q;
        const __bf16* qrow = qbuf + g * 2048 + h * 128;
        #pragma unroll
        for (int dt = 0; dt < 4; dt++)
            qf[rt][dt] = *reinterpret_cast<const bf16x8*>(qrow + 32 * dt + 8 * quad);
        const __bf16* qrr = qrot + g * 1024 + h * 64;
        qf[rt][4] = *reinterpret_cast<const bf16x8*>(qrr + 8 * quad);
        qf[rt][5] = *reinterpret_cast<const bf16x8*>(qrr + 32 + 8 * quad);
    }

    f32x4 o[2][8];
    float m_i[2][4], l_i[2][4];
    #pragma unroll
    for (int rt = 0; rt < 2; rt++) {
        #pragma unroll
        for (int dt = 0; dt < 8; dt++) { o[rt][dt][0]=0.f; o[rt][dt][1]=0.f; o[rt][dt][2]=0.f; o[rt][dt][3]=0.f; }
        #pragma unroll
        for (int r = 0; r < 4; r++) { m_i[rt][r] = -INFINITY; l_i[rt][r] = 0.f; }
    }

    const int nunits = 2 * qi + 2;
    const size_t urow = (size_t)b * T_SEQ;
    for (int u = 0; u < nunits; u++) {
        const int k0 = 64 * u;

        // ---- stage K nope [k][0..127]: coalesced vector copies ----
        #pragma unroll
        for (int p = 0; p < 4; p++) {
            int c = tid + 256 * p;
            int row = c >> 4, seg = (c & 15) * 8;
            *reinterpret_cast<bf16x8*>(Ks + row * KS + seg) =
                *reinterpret_cast<const bf16x8*>(ukv + (urow + k0 + row) * 4096 + h * 256 + seg);
        }
        // ---- stage K rope [k][128..191]: pre-roped, contiguous copy ----
        #pragma unroll
        for (int p = 0; p < 2; p++) {
            int c = tid + 256 * p;
            int row = c >> 3, seg = (c & 7) * 8;
            *reinterpret_cast<bf16x8*>(Ks + row * KS + 128 + seg) =
                *reinterpret_cast<const bf16x8*>(krot + (urow + k0 + row) * 64 + seg);
        }
        // ---- stage Vt: flat 18KB copy from pre-transposed tile ----
        {
            const uint4* vsrc = reinterpret_cast<const uint4*>(vtt + ((size_t)bh * 32 + u) * (128 * VS));
            uint4* vdst = reinterpret_cast<uint4*>(Vt);
            for (int c = tid; c < 1152; c += 256) vdst[c] = vsrc[c];
        }
        __syncthreads();

        // ---- S = Q K^T ----
        f32x4 s[2][4] = {};
        #pragma unroll
        for (int kt = 0; kt < 4; kt++) {
            #pragma unroll
            for (int dt = 0; dt < 6; dt++) {
                bf16x8 kf = *reinterpret_cast<const bf16x8*>(Ks + (16 * kt + l15) * KS + 32 * dt + 8 * quad);
                s[0][kt] = __builtin_amdgcn_mfma_f32_16x16x32_bf16(qf[0][dt], kf, s[0][kt], 0, 0, 0);
                s[1][kt] = __builtin_amdgcn_mfma_f32_16x16x32_bf16(qf[1][dt], kf, s[1][kt], 0, 0, 0);
            }
        }

        // ---- causal mask (only near-diagonal units) + online softmax ----
        const bool domask = (u + 2 >= nunits);
        #pragma unroll
        for (int rt = 0; rt < 2; rt++) {
            #pragma unroll
            for (int r = 0; r < 4; r++) {
                const int q = q0 + 32 * w + 16 * rt + 4 * quad + r;
                float sv[4];
                #pragma unroll
                for (int kt = 0; kt < 4; kt++) {
                    float v = s[rt][kt][r] * SCALE;
                    if (domask && (k0 + 16 * kt + l15 > q)) v = -INFINITY;
                    sv[kt] = v;
                }
                float rmax = fmaxf(fmaxf(sv[0], sv[1]), fmaxf(sv[2], sv[3]));
                rmax = fmaxf(rmax, __shfl_xor(rmax, 1, 64));
                rmax = fmaxf(rmax, __shfl_xor(rmax, 2, 64));
                rmax = fmaxf(rmax, __shfl_xor(rmax, 4, 64));
                rmax = fmaxf(rmax, __shfl_xor(rmax, 8, 64));
                float mnew  = fmaxf(m_i[rt][r], rmax);
                float alpha = __expf(m_i[rt][r] - mnew);
                m_i[rt][r] = mnew;
                float sum = 0.f;
                #pragma unroll
                for (int kt = 0; kt < 4; kt++) {
                    float pv = __expf(sv[kt] - mnew);
                    sum += pv;
                    Psh[(32 * w + 16 * rt + 4 * quad + r) * PS + 16 * kt + l15] = (__bf16)pv;
                }
                sum += __shfl_xor(sum, 1, 64);
                sum += __shfl_xor(sum, 2, 64);
                sum += __shfl_xor(sum, 4, 64);
                sum += __shfl_xor(sum, 8, 64);
                l_i[rt][r] = l_i[rt][r] * alpha + sum;
                #pragma unroll
                for (int dt = 0; dt < 8; dt++) o[rt][dt][r] *= alpha;
            }
        }
        // No barrier: Psh rows [32w,32w+32) are written and read by wave w only.

        // ---- O += P V ----
        #pragma unroll
        for (int kh = 0; kh < 2; kh++) {
            bf16x8 pf0 = *reinterpret_cast<const bf16x8*>(Psh + (32 * w + l15) * PS + 32 * kh + 8 * quad);
            bf16x8 pf1 = *reinterpret_cast<const bf16x8*>(Psh + (32 * w + 16 + l15) * PS + 32 * kh + 8 * quad);
            #pragma unroll
            for (int dt = 0; dt < 8; dt++) {
                bf16x8 vf = *reinterpret_cast<const bf16x8*>(Vt + (16 * dt + l15) * VS + 32 * kh + 8 * quad);
                o[0][dt] = __builtin_amdgcn_mfma_f32_16x16x32_bf16(pf0, vf, o[0][dt], 0, 0, 0);
                o[1][dt] = __builtin_amdgcn_mfma_f32_16x16x32_bf16(pf1, vf, o[1][dt], 0, 0, 0);
            }
        }
        __syncthreads();   // all reads of Ks/Vt done before next stage
    }

    // ---- epilogue (bf16 out) ----
    #pragma unroll
    for (int rt = 0; rt < 2; rt++) {
        #pragma unroll
        for (int r = 0; r < 4; r++) {
            const int q = q0 + 32 * w + 16 * rt + 4 * quad + r;
            const float inv = 1.0f / l_i[rt][r];
            size_t base = ((size_t)b * T_SEQ + q) * 2048 + h * 128;
            #pragma unroll
            for (int dt = 0; dt < 8; dt++)
                obuf[base + 16 * dt + l15] = (__bf16)(o[rt][dt][r] * inv);
        }
    }
}

extern "C" void kernel_launch(void* const* d_in, const int* in_sizes, int n_in,
                              void* d_out, int out_size, void* d_ws, size_t ws_size,
                              hipStream_t stream)
{
    const float* x      = (const float*)d_in[0];
    const float* w_q    = (const float*)d_in[1];
    const float* w_dkv  = (const float*)d_in[2];
    const float* w_ukv  = (const float*)d_in[3];
    const float* w_o    = (const float*)d_in[4];
    const float* w_qrot = (const float*)d_in[5];
    const float* w_krot = (const float*)d_in[6];
    float* out = (float*)d_out;

    const size_t M = 4096;
    __bf16* ws   = (__bf16*)d_ws;
    __bf16* xb   = ws;                    // 4096x2048
    __bf16* wqb  = xb   + M * 2048;       // 2048x2048
    __bf16* wdkb = wqb  + 2048 * 2048;    // 512x2048
    __bf16* wukb = wdkb + 512 * 2048;     // 4096x512
    __bf16* wob  = wukb + 4096 * 512;     // 2048x2048
    __bf16* wqrb = wob  + 2048 * 2048;    // 1024x2048
    __bf16* wkrb = wqrb + 1024 * 2048;    // 64x2048
    __bf16* qb   = wkrb + 64 * 2048;      // 4096x2048
    __bf16* qr   = qb   + M * 2048;       // 4096x1024 (roped in place)
    __bf16* kr   = qr   + M * 1024;       // 4096x64   (roped in place)
    __bf16* dkv  = kr   + M * 64;         // 4096x512
    __bf16* ukv  = dkv  + M * 512;        // 4096x4096
    __bf16* ao   = ukv  + M * 4096;       // 4096x2048
    __bf16* vtt  = ao   + M * 2048;       // 32*32*128*72 (~18.9MB)  total ~143MB

    dim3 blk(256);
    cast_bf16<<<4096, blk, 0, stream>>>(x,      xb,   4096 * 2048);
    cast_bf16<<<2048, blk, 0, stream>>>(w_q,    wqb,  2048 * 2048);
    cast_bf16<<<512,  blk, 0, stream>>>(w_dkv,  wdkb, 512 * 2048);
    cast_bf16<<<1024, blk, 0, stream>>>(w_ukv,  wukb, 4096 * 512);
    cast_bf16<<<2048, blk, 0, stream>>>(w_o,    wob,  2048 * 2048);
    cast_bf16<<<1024, blk, 0, stream>>>(w_qrot, wqrb, 1024 * 2048);
    cast_bf16<<<64,   blk, 0, stream>>>(w_krot, wkrb, 64 * 2048);

    gemm_bt_mfma<__bf16><<<dim3(16, 32), blk, 0, stream>>>(xb,  wqb,  qb,  4096, 2048, 2048);
    gemm_bt_mfma<__bf16><<<dim3(8,  32), blk, 0, stream>>>(xb,  wqrb, qr,  4096, 1024, 2048);
    gemm_bt_mfma<__bf16><<<dim3(1,  32), blk, 0, stream>>>(xb,  wkrb, kr,  4096, 64,   2048);
    gemm_bt_mfma<__bf16><<<dim3(4,  32), blk, 0, stream>>>(xb,  wdkb, dkv, 4096, 512,  2048);
    gemm_bt_mfma<__bf16><<<dim3(32, 32), blk, 0, stream>>>(dkv, wukb, ukv, 4096, 4096, 512);

    rope_ip<<<8192, blk, 0, stream>>>(qr, 9, 4096 * 512);   // 16 heads * 32 pairs
    rope_ip<<<512,  blk, 0, stream>>>(kr, 5, 4096 * 32);    // 1 block  * 32 pairs
    prep_v<<<dim3(32, 32), blk, 0, stream>>>(ukv, vtt);

    flash_mfma<<<dim3(16, 32), blk, 0, stream>>>(qb, qr, kr, ukv, vtt, ao);
    gemm_bt_mfma<float><<<dim3(16, 32), blk, 0, stream>>>(ao, wob, out, 4096, 2048, 2048);
}